// Round 14
// baseline (659.238 us; speedup 1.0000x reference)
//
#include <hip/hip_runtime.h>
#include <math.h>

#define TT 512
#define BB 512
#define FF 14
#define H1 32
#define H2 64

typedef _Float16 h2v __attribute__((ext_vector_type(2)));

__device__ __forceinline__ float rcpf_(float x) { return __builtin_amdgcn_rcpf(x); }
__device__ __forceinline__ float sigmoidf_(float x) {
    return rcpf_(1.0f + __expf(-x));
}
__device__ __forceinline__ float tanhf_(float x) {
    float e = __expf(-2.0f * fabsf(x));
    float t = (1.0f - e) * rcpf_(1.0f + e);
    return copysignf(t, x);
}
__device__ __forceinline__ float fdot2_(h2v a, h2v b, float c) {
#if __has_builtin(__builtin_amdgcn_fdot2)
    return __builtin_amdgcn_fdot2(a, b, c, false);
#else
    return fmaf((float)a.x, (float)b.x, fmaf((float)a.y, (float)b.y, c));
#endif
}
__device__ __forceinline__ h2v bc_(unsigned u) { return __builtin_bit_cast(h2v, u); }
__device__ __forceinline__ h2v pk_(float lo, float hi) {
    h2v r; r.x = (_Float16)lo; r.y = (_Float16)hi; return r;
}
// DPP: 0xB1 = quad_perm[1,0,3,2] (xor1), 0x4E = quad_perm[2,3,0,1] (xor2),
// 0x100+N = row_shl N (dest lane l gets src lane l+N within 16-lane row).
template <int CTRL>
__device__ __forceinline__ float dpp_mov(float v) {
    return __int_as_float(__builtin_amdgcn_update_dpp(
        0, __float_as_int(v), CTRL, 0xF, 0xF, true));
}

// TWO rows per block, 256 blocks = 1 block/CU, 512 threads (8 balanced waves).
// R13 post-mortem: DS-pipe instr throughput + ws1 bank conflicts bound the
// step. This round: (1) L2 dot QUARTER-split — lane (u2,t2,q2) computes
// quarter-dots of TWO gates (t=0: i_u,g_u; t=1: f_u,o_u) over one shared
// 3xb128 state slice -> L2 state reads halve; quarter addresses hit disjoint
// bank groups (conflict-free). Reduce: quad_perm 0xB1+0x4E butterflies +
// row_shl4 o-gather. (2) w1 back in VGPRs (12 dw; 36 dw total/lane, R7-proven)
// -> ws1 LDS table and its 4-way conflicts deleted. L1 mapping, owners,
// parities, staging, init, MLP verbatim from R13 (absmax 0.0).
__global__ __launch_bounds__(512) void lstm3_kernel(
    const float* __restrict__ x,
    const float* __restrict__ Wih1, const float* __restrict__ Whh1,
    const float* __restrict__ bih1, const float* __restrict__ bhh1,
    const float* __restrict__ Wih2, const float* __restrict__ Whh2,
    const float* __restrict__ bih2, const float* __restrict__ bhh2,
    const float* __restrict__ Wfc1, const float* __restrict__ bfc1,
    const float* __restrict__ Wfc2, const float* __restrict__ bfc2,
    const float* __restrict__ Wfc,  const float* __restrict__ bfc,
    float* __restrict__ out)
{
    const int row0 = 2 * blockIdx.x;
    const int l    = threadIdx.x;

    // Packed f16-pair state per [parity][row]:
    // s2cat: 48 dw = [h1 (16 dw) | h2 (32 dw)] ; s1cat: 24 dw = [x|pad|h1]
    __shared__ __align__(16) unsigned s2cat[2][2][48];
    __shared__ __align__(16) unsigned s1cat[2][2][24];
    __shared__ float mlp1[2][8];
    __shared__ float mlp2[2][8];

    // ---- L2 role: quarter q2, pair t2, unit u2 ----
    const int q2 = l & 3;            // quarter of the 96-f16 state
    const int t2 = (l >> 2) & 1;     // 0: gates (i_u, g_u); 1: (f_u, o_u)
    const int u2 = l >> 3;           // 0..63
    // ---- L1 role (R13 verbatim): unit u1, row rw1, type, half ----
    const int u1  = l >> 4;          // 0..31
    const int rw1 = (l >> 3) & 1;
    const int hf1 = l & 1;
    const int r1  = 32 * ((l >> 1) & 3) + u1;

    // ---- layer-2 weights: 2 gates x quarter (12 f16 pairs each) in VGPRs ----
    const int gA = t2 ? (u2 + 64) : u2;         // i or f
    const int gB = gA + 128;                    // g or o
    h2v w2a[12], w2b[12];
    {
        // f16 index range [24*q2, 24*q2+24) of [Wih2 row (32) | Whh2 row (64)]
        #pragma unroll
        for (int j = 0; j < 12; ++j) {
            const int i0 = 24 * q2 + 2 * j;
            const float aLo = (i0     < H1) ? Wih2[gA * H1 + i0]       : Whh2[gA * H2 + i0 - H1];
            const float aHi = (i0 + 1 < H1) ? Wih2[gA * H1 + i0 + 1]   : Whh2[gA * H2 + i0 + 1 - H1];
            const float bLo = (i0     < H1) ? Wih2[gB * H1 + i0]       : Whh2[gB * H2 + i0 - H1];
            const float bHi = (i0 + 1 < H1) ? Wih2[gB * H1 + i0 + 1]   : Whh2[gB * H2 + i0 + 1 - H1];
            w2a[j] = pk_(aLo, aHi);
            w2b[j] = pk_(bLo, bHi);
        }
    }
    const float bA = (q2 == 0) ? (bih2[gA] + bhh2[gA]) : 0.0f;
    const float bB = (q2 == 0) ? (bih2[gB] + bhh2[gB]) : 0.0f;

    // ---- layer-1 weights: 12 dw in VGPRs (R13's ws1 builder, per lane) ----
    h2v w1v[12];
    {
        if (hf1 == 0) {
            float tmp[16];
            #pragma unroll
            for (int k = 0; k < FF; ++k) tmp[k] = Wih1[r1 * FF + k];
            tmp[14] = 0.0f; tmp[15] = 0.0f;
            #pragma unroll
            for (int j = 0; j < 8; ++j) w1v[j] = pk_(tmp[2 * j], tmp[2 * j + 1]);
            const float4* q = (const float4*)(Whh1 + r1 * H1);
            float4 v = q[0];
            w1v[8] = pk_(v.x, v.y); w1v[9] = pk_(v.z, v.w);
            v = q[1];
            w1v[10] = pk_(v.x, v.y); w1v[11] = pk_(v.z, v.w);
        } else {
            const float4* q = (const float4*)(Whh1 + r1 * H1);
            #pragma unroll
            for (int k = 0; k < 6; ++k) {
                float4 v = q[2 + k];
                w1v[2 * k] = pk_(v.x, v.y); w1v[2 * k + 1] = pk_(v.z, v.w);
            }
        }
    }
    const float b1r = (hf1 == 0) ? (bih1[r1] + bhh1[r1]) : 0.0f;

    float c1r  = 0.0f;   // layer-1 cell state for (u1, rw1): owner lanes
    float xreg = 0.0f;   // x prefetch

    // x staging on owner lanes (R13 verbatim): u2 in [16,30)->row0, [32,46)->row1
    int fidx = -1, frr = 0;
    if ((l & 7) == 0) {
        if (u2 >= 16 && u2 < 16 + FF)      { fidx = u2 - 16; frr = 0; }
        else if (u2 >= 32 && u2 < 32 + FF) { fidx = u2 - 32; frr = 1; }
    }

    // ---- init zeros + x(0)/x(1) (R13 verbatim) ----
    if (l < 96) { const int rr = (l >= 48); s2cat[0][rr][l - 48 * rr] = 0u; }
    if (l >= 96 && l < 130) {
        const int Li = l - 96; const int rr = (Li >= 17);
        s1cat[0][rr][7 + Li - 17 * rr] = 0u;
    }
    if (l == 192) s1cat[1][0][7] = 0u;
    if (l == 193) s1cat[1][1][7] = 0u;
    if (fidx >= 0) {
        ((_Float16*)s1cat[0][frr])[fidx] =
            (_Float16)x[((size_t)0 * BB + row0 + frr) * FF + fidx];
        xreg = x[((size_t)1 * BB + row0 + frr) * FF + fidx];
    }
    __syncthreads();

    // ---- pipelined time loop: ONE barrier per iteration ----
    for (int i = 0; i <= TT; ++i) {
        const int rp = (i - 1) & 1;
        const int cp = i & 1;
        const int np = cp ^ 1;

        // ===== layer-2: quarter-dots for 2 gates, both rows (step i-1) =====
        if (i > 0) {
            #pragma unroll
            for (int rr = 0; rr < 2; ++rr) {
                const uint4* sv = ((const uint4*)s2cat[rp][rr]) + q2 * 3;
                float pa0 = bA, pa1 = 0.f, pb0 = bB, pb1 = 0.f;
                #pragma unroll
                for (int k = 0; k < 3; ++k) {
                    uint4 u = sv[k];
                    pa0 = fdot2_(w2a[4 * k + 0], bc_(u.x), pa0);
                    pa1 = fdot2_(w2a[4 * k + 1], bc_(u.y), pa1);
                    pa0 = fdot2_(w2a[4 * k + 2], bc_(u.z), pa0);
                    pa1 = fdot2_(w2a[4 * k + 3], bc_(u.w), pa1);
                    pb0 = fdot2_(w2b[4 * k + 0], bc_(u.x), pb0);
                    pb1 = fdot2_(w2b[4 * k + 1], bc_(u.y), pb1);
                    pb0 = fdot2_(w2b[4 * k + 2], bc_(u.z), pb0);
                    pb1 = fdot2_(w2b[4 * k + 3], bc_(u.w), pb1);
                }
                float pa = pa0 + pa1;          // gate A partial (quarter q2)
                float pb = pb0 + pb1;          // gate B partial
                pa += dpp_mov<0xB1>(pa);       // xor1
                pa += dpp_mov<0x4E>(pa);       // xor2 -> full gate-A sum
                pb += dpp_mov<0xB1>(pb);
                pb += dpp_mov<0x4E>(pb);       // full gate-B sum
                const float ob = dpp_mov<0x104>(pb);  // o_u from t=1 quad
                if ((l & 7) == 0) {
                    // lane has i_u (pa), g_u (pb), o_u (ob); f unused (cell=0)
                    const float cn = sigmoidf_(pa) * tanhf_(pb >= 0.f ?  // tanh(g)
                                     (1.0f - __expf(-2.0f * pb)) * rcpf_(1.0f + __expf(-2.0f * pb)) :
                                    -(1.0f - __expf( 2.0f * pb)) * rcpf_(1.0f + __expf( 2.0f * pb)));
                    ((_Float16*)s2cat[cp][rr])[32 + u2] =
                        (_Float16)(sigmoidf_(ob) * tanhf_(cn));
                }
            }
        }

        // ===== layer-1: half-dots, one (gate,half,row) slot (step i) =====
        if (i < TT) {
            const uint4* sv = ((const uint4*)s1cat[cp][rw1]) + hf1 * 3;
            float a0 = b1r, a1 = 0.f, a2 = 0.f, a3 = 0.f;
            #pragma unroll
            for (int k = 0; k < 3; ++k) {
                uint4 u = sv[k];
                a0 = fdot2_(w1v[4 * k + 0], bc_(u.x), a0);
                a1 = fdot2_(w1v[4 * k + 1], bc_(u.y), a1);
                a2 = fdot2_(w1v[4 * k + 2], bc_(u.z), a2);
                a3 = fdot2_(w1v[4 * k + 3], bc_(u.w), a3);
            }
            float g = (a0 + a1) + (a2 + a3);
            g += dpp_mov<0xB1>(g);
            const float fg = dpp_mov<0x102>(g);
            const float gg = dpp_mov<0x104>(g);
            const float og = dpp_mov<0x106>(g);
            if ((l & 7) == 0) {
                const float cn = sigmoidf_(fg) * c1r + sigmoidf_(g) * tanhf_(gg);
                c1r = cn;
                const _Float16 hh = (_Float16)(sigmoidf_(og) * tanhf_(cn));
                ((_Float16*)s1cat[np][rw1])[16 + u1] = hh;  // L1, step i+1
                ((_Float16*)s2cat[cp][rw1])[u1]      = hh;  // L2, step i
            }
            // ----- stage x(i+1), prefetch x(i+2) -----
            if (fidx >= 0) {
                ((_Float16*)s1cat[np][frr])[fidx] = (_Float16)xreg;
                const int tn = (i + 2 < TT) ? (i + 2) : (TT - 1);
                xreg = x[((size_t)tn * BB + row0 + frr) * FF + fidx];
            }
        }
        __syncthreads();
    }

    // ---- MLP head, both rows (R13 verbatim) ----
    if (l < 16) {
        const int rr = l >> 3, j = l & 7;
        const _Float16* h2p = (const _Float16*)s2cat[0][rr];
        float a = bfc1[j];
        #pragma unroll
        for (int k = 0; k < H2; ++k)
            a = fmaf(fmaxf((float)h2p[32 + k], 0.0f), Wfc1[j * H2 + k], a);
        mlp1[rr][j] = fmaxf(a, 0.0f);
    }
    __syncthreads();
    if (l < 16) {
        const int rr = l >> 3, j = l & 7;
        float a = bfc2[j];
        #pragma unroll
        for (int k = 0; k < 8; ++k) a = fmaf(mlp1[rr][k], Wfc2[j * 8 + k], a);
        mlp2[rr][j] = fmaxf(a, 0.0f);
    }
    __syncthreads();
    if (l < 2) {
        float a = bfc[0];
        #pragma unroll
        for (int k = 0; k < 8; ++k) a = fmaf(mlp2[l][k], Wfc[k], a);
        out[row0 + l] = a;
    }
}

extern "C" void kernel_launch(void* const* d_in, const int* in_sizes, int n_in,
                              void* d_out, int out_size, void* d_ws, size_t ws_size,
                              hipStream_t stream) {
    const float* x    = (const float*)d_in[0];
    const float* Wih1 = (const float*)d_in[1];
    const float* Whh1 = (const float*)d_in[2];
    const float* bih1 = (const float*)d_in[3];
    const float* bhh1 = (const float*)d_in[4];
    const float* Wih2 = (const float*)d_in[5];
    const float* Whh2 = (const float*)d_in[6];
    const float* bih2 = (const float*)d_in[7];
    const float* bhh2 = (const float*)d_in[8];
    const float* Wfc1 = (const float*)d_in[9];
    const float* bfc1 = (const float*)d_in[10];
    const float* Wfc2 = (const float*)d_in[11];
    const float* bfc2 = (const float*)d_in[12];
    const float* Wfc  = (const float*)d_in[13];
    const float* bfc  = (const float*)d_in[14];
    float* out = (float*)d_out;

    lstm3_kernel<<<dim3(BB / 2), dim3(512), 0, stream>>>(
        x, Wih1, Whh1, bih1, bhh1, Wih2, Whh2, bih2, bhh2,
        Wfc1, bfc1, Wfc2, bfc2, Wfc, bfc, out);
}

// Round 15
// 489.171 us; speedup vs baseline: 1.3477x; 1.3477x over previous
//
#include <hip/hip_runtime.h>
#include <math.h>

#define TT 512
#define BB 512
#define FF 14
#define H1 32
#define H2 64
#define NR 16               // rows (batch cols) per block
#define NBLK (BB / NR)      // 32 blocks

typedef _Float16 half8  __attribute__((ext_vector_type(8)));
typedef float    float4v __attribute__((ext_vector_type(4)));

__device__ __forceinline__ float rcpf_(float x) { return __builtin_amdgcn_rcpf(x); }
__device__ __forceinline__ float sigmoidf_(float x) { return rcpf_(1.0f + __expf(-x)); }
__device__ __forceinline__ float tanhf_(float x) {
    float e = __expf(-2.0f * fabsf(x));
    float t = (1.0f - e) * rcpf_(1.0f + e);
    return copysignf(t, x);
}
__device__ __forceinline__ float4v mfma16(half8 a, half8 b, float4v c) {
    return __builtin_amdgcn_mfma_f32_16x16x32_f16(a, b, c, 0, 0, 0);
}

// B-fragment store helper: element (k, n) of a B operand lives at
// lane = n + 16*((k&31)>>3 & 3), dword = (k&31)>>1 & 3, half = k&1, slab = k>>5.
// Returns HALF-index into the (unsigned*) frag area (256 dw per slab).
__device__ __forceinline__ int bfrag_off(int k, int n) {
    const int slab = k >> 5, k5 = k & 31;
    const int dl = n + 16 * ((k5 >> 3) & 3);
    const int dw = (k5 >> 1) & 3;
    return ((slab * 256 + dl * 4 + dw) << 1) | (k5 & 1);
}

// 16 rows per block, 32 blocks, 512 threads (8 waves). Per step: layer-2 =
// M256/N16/K96 f16 MFMA (2 tiles/wave x 3 K-slabs), layer-1 = M128/K64
// (1 tile/wave x 2 slabs). M ordering m=4*unit+gate so the C-layout
// (col=lane&15,row=quad*4+reg) gives each lane i,f,g,o of one unit in its 4
// accumulator regs: activations are per-lane fp32, NO cross-lane, NO exec
// masking, c1 is a per-lane register. Weights live in A-fragments in VGPRs
// (loaded once); bias rides in the C operand. State is stored in B-fragment
// order in LDS: lane-linear ds_read_b128 per slab. One barrier/step, R12
// pipeline parities.
__global__ __launch_bounds__(512)
__attribute__((amdgpu_waves_per_eu(2, 2)))
void lstm3_kernel(
    const float* __restrict__ x,
    const float* __restrict__ Wih1, const float* __restrict__ Whh1,
    const float* __restrict__ bih1, const float* __restrict__ bhh1,
    const float* __restrict__ Wih2, const float* __restrict__ Whh2,
    const float* __restrict__ bih2, const float* __restrict__ bhh2,
    const float* __restrict__ Wfc1, const float* __restrict__ bfc1,
    const float* __restrict__ Wfc2, const float* __restrict__ bfc2,
    const float* __restrict__ Wfc,  const float* __restrict__ bfc,
    float* __restrict__ out)
{
    const int row0 = blockIdx.x * NR;
    const int l    = threadIdx.x;
    const int lane = l & 63;
    const int w    = l >> 6;        // wave 0..7
    const int n    = lane & 15;     // batch col within block
    const int quad = lane >> 4;

    // B-fragment state areas, [parity][slab*256 + lane*4 + dw] dwords.
    // s2f: K=96 (3 slabs): [h1 k=0..31 | h2 k=32..95]
    // s1f: K=64 (2 slabs): [x k=0..13 | pad | h1 k=16..47 | pad k=48..63]
    __shared__ __align__(16) unsigned s2f[2][3 * 256];
    __shared__ __align__(16) unsigned s1f[2][2 * 256];
    __shared__ _Float16 h2plain[NR][H2];
    __shared__ float mlp1[NR][8];
    __shared__ float mlp2[NR][8];

    // ---------------- A-fragments (weights), loaded once ----------------
    // L2: tiles T0=2w, T1=2w+1; A[m][k]: m = T*16 + (lane&15), k = s*32+quad*8+j
    half8 a2[2][3];
    float4v bias2[2];
    #pragma unroll
    for (int tt = 0; tt < 2; ++tt) {
        const int T = 2 * w + tt;
        const int m = T * 16 + n;
        const int row = (m & 3) * 64 + (m >> 2);   // orig gate row (i|f|g|o blocks)
        #pragma unroll
        for (int s = 0; s < 3; ++s) {
            const int k0 = s * 32 + quad * 8;
            half8 a;
            if (k0 < H1) {
                #pragma unroll
                for (int j = 0; j < 8; ++j) a[j] = (_Float16)Wih2[row * H1 + k0 + j];
            } else {
                #pragma unroll
                for (int j = 0; j < 8; ++j) a[j] = (_Float16)Whh2[row * H2 + (k0 - H1) + j];
            }
            a2[tt][s] = a;
        }
        const int u = T * 4 + quad;
        #pragma unroll
        for (int r = 0; r < 4; ++r) {
            const int br = r * 64 + u;
            bias2[tt][r] = bih2[br] + bhh2[br];
        }
    }

    // L1: tile w; A rows m = w*16 + n -> orig row (m&3)*32 + (m>>2)
    half8 a1[2];
    float4v bias1;
    {
        const int m = w * 16 + n;
        const int row = (m & 3) * 32 + (m >> 2);   // 0..127
        #pragma unroll
        for (int s = 0; s < 2; ++s) {
            const int k0 = s * 32 + quad * 8;
            half8 a;
            #pragma unroll
            for (int j = 0; j < 8; ++j) {
                const int k = k0 + j;
                float v = 0.0f;
                if (k < FF)                 v = Wih1[row * FF + k];
                else if (k >= 16 && k < 48) v = Whh1[row * H1 + (k - 16)];
                a[j] = (_Float16)v;
            }
            a1[s] = a;
        }
        const int u1 = w * 4 + quad;
        #pragma unroll
        for (int r = 0; r < 4; ++r) {
            const int br = r * 32 + u1;
            bias1[r] = bih1[br] + bhh1[br];
        }
    }

    // ---------------- precomputed write offsets (half-indices) ----------------
    const int u1   = w * 4 + quad;                  // layer-1 unit of this lane
    const int offB = bfrag_off(u1, n);              // h1 -> s2f slab0
    const int offA = bfrag_off(16 + u1, n);         // h1 -> s1f
    int off2[2];
    #pragma unroll
    for (int tt = 0; tt < 2; ++tt)
        off2[tt] = bfrag_off(32 + (2 * w + tt) * 4 + quad, n);   // h2 -> s2f

    // x stager (lanes 0..55): 4 elements each, flat fi = l*4+e over [16 rows][14]
    int offx[4]; int xact = (l < 56);
    #pragma unroll
    for (int e = 0; e < 4; ++e) {
        const int fi = l * 4 + e;
        const int nr = fi / FF, fe = fi - nr * FF;
        offx[e] = (fi < NR * FF) ? bfrag_off(fe, nr) : -1;
    }
    const size_t xbase = (size_t)row0 * FF + l * 4;

    float c1r = 0.0f;   // layer-1 cell state for (u1, n) — per-lane!

    // ---------------- init: zero frag areas, stage x(0) ----------------
    for (int z = l; z < 2 * 3 * 256; z += 512) ((unsigned*)s2f)[z] = 0u;
    for (int z = l; z < 2 * 2 * 256; z += 512) ((unsigned*)s1f)[z] = 0u;
    if (l < NR * H2 / 2) ((unsigned*)h2plain)[l] = 0u;
    if (xact) {
        const float4 xv = *(const float4*)(x + xbase);   // t = 0
        const float xe[4] = {xv.x, xv.y, xv.z, xv.w};
        #pragma unroll
        for (int e = 0; e < 4; ++e)
            if (offx[e] >= 0) ((_Float16*)s1f[0])[offx[e]] = (_Float16)xe[e];
    }
    __syncthreads();

    // ---------------- pipelined time loop: ONE barrier/iteration ----------------
    for (int i = 0; i <= TT; ++i) {
        const int rp = (i - 1) & 1;
        const int cp = i & 1;
        const int np = cp ^ 1;

        // ===== layer-1 for step i =====
        if (i < TT) {
            const half8 b0 = *(const half8*)(s1f[cp] + lane * 4);
            const half8 b1 = *(const half8*)(s1f[cp] + 256 + lane * 4);
            float4v acc = bias1;
            acc = mfma16(a1[0], b0, acc);
            acc = mfma16(a1[1], b1, acc);
            // lane holds (i,f,g,o) preacts of unit u1, col n
            const float cn = sigmoidf_(acc[1]) * c1r + sigmoidf_(acc[0]) * tanhf_(acc[2]);
            c1r = cn;
            const _Float16 hh = (_Float16)(sigmoidf_(acc[3]) * tanhf_(cn));
            ((_Float16*)s1f[np])[offA] = hh;   // for layer-1, step i+1
            ((_Float16*)s2f[cp])[offB] = hh;   // for layer-2, step i
            // stage x(i+1) into s1f[np]
            if (xact) {
                const int tn = (i + 1 < TT) ? (i + 1) : (TT - 1);
                const float4 xv = *(const float4*)(x + (size_t)tn * BB * FF + xbase);
                const float xe[4] = {xv.x, xv.y, xv.z, xv.w};
                #pragma unroll
                for (int e = 0; e < 4; ++e)
                    if (offx[e] >= 0) ((_Float16*)s1f[np])[offx[e]] = (_Float16)xe[e];
            }
        }

        // ===== layer-2 for step i-1 =====
        if (i > 0) {
            const half8 b0 = *(const half8*)(s2f[rp] + lane * 4);
            const half8 b1 = *(const half8*)(s2f[rp] + 256 + lane * 4);
            const half8 b2 = *(const half8*)(s2f[rp] + 512 + lane * 4);
            #pragma unroll
            for (int tt = 0; tt < 2; ++tt) {
                float4v acc = bias2[tt];
                acc = mfma16(a2[tt][0], b0, acc);
                acc = mfma16(a2[tt][1], b1, acc);
                acc = mfma16(a2[tt][2], b2, acc);
                // lane holds (i,f,g,o) of unit u = (2w+tt)*4+quad, col n
                const float cn = sigmoidf_(acc[0]) * tanhf_(acc[2]);
                const float h  = sigmoidf_(acc[3]) * tanhf_(cn);
                ((_Float16*)s2f[cp])[off2[tt]] = (_Float16)h;
                if (i == TT) h2plain[n][(2 * w + tt) * 4 + quad] = (_Float16)h;
            }
        }
        __syncthreads();
    }

    // ---------------- MLP head (16 rows) ----------------
    if (l < NR * 8) {
        const int rr = l >> 3, j = l & 7;
        float a = bfc1[j];
        #pragma unroll
        for (int k = 0; k < H2; ++k)
            a = fmaf(fmaxf((float)h2plain[rr][k], 0.0f), Wfc1[j * H2 + k], a);
        mlp1[rr][j] = fmaxf(a, 0.0f);
    }
    __syncthreads();
    if (l < NR * 8) {
        const int rr = l >> 3, j = l & 7;
        float a = bfc2[j];
        #pragma unroll
        for (int k = 0; k < 8; ++k) a = fmaf(mlp1[rr][k], Wfc2[j * 8 + k], a);
        mlp2[rr][j] = fmaxf(a, 0.0f);
    }
    __syncthreads();
    if (l < NR) {
        float a = bfc[0];
        #pragma unroll
        for (int k = 0; k < 8; ++k) a = fmaf(mlp2[l][k], Wfc[k], a);
        out[row0 + l] = a;
    }
}

extern "C" void kernel_launch(void* const* d_in, const int* in_sizes, int n_in,
                              void* d_out, int out_size, void* d_ws, size_t ws_size,
                              hipStream_t stream) {
    const float* x    = (const float*)d_in[0];
    const float* Wih1 = (const float*)d_in[1];
    const float* Whh1 = (const float*)d_in[2];
    const float* bih1 = (const float*)d_in[3];
    const float* bhh1 = (const float*)d_in[4];
    const float* Wih2 = (const float*)d_in[5];
    const float* Whh2 = (const float*)d_in[6];
    const float* bih2 = (const float*)d_in[7];
    const float* bhh2 = (const float*)d_in[8];
    const float* Wfc1 = (const float*)d_in[9];
    const float* bfc1 = (const float*)d_in[10];
    const float* Wfc2 = (const float*)d_in[11];
    const float* bfc2 = (const float*)d_in[12];
    const float* Wfc  = (const float*)d_in[13];
    const float* bfc  = (const float*)d_in[14];
    float* out = (float*)d_out;

    lstm3_kernel<<<dim3(NBLK), dim3(512), 0, stream>>>(
        x, Wih1, Whh1, bih1, bhh1, Wih2, Whh2, bih2, bhh2,
        Wfc1, bfc1, Wfc2, bfc2, Wfc, bfc, out);
}

// Round 16
// 406.455 us; speedup vs baseline: 1.6219x; 1.2035x over previous
//
#include <hip/hip_runtime.h>
#include <math.h>

#define TT 512
#define BB 512
#define FF 14
#define H1 32
#define H2 64
#define NR 16               // rows (batch cols) per block
#define NBLK (BB / NR)      // 32 blocks

typedef _Float16 half8  __attribute__((ext_vector_type(8)));
typedef float    float4v __attribute__((ext_vector_type(4)));

__device__ __forceinline__ float rcpf_(float x) { return __builtin_amdgcn_rcpf(x); }
__device__ __forceinline__ float sigmoidf_(float x) { return rcpf_(1.0f + __expf(-x)); }
__device__ __forceinline__ float tanhf_(float x) {
    float e = __expf(-2.0f * fabsf(x));
    float t = (1.0f - e) * rcpf_(1.0f + e);
    return copysignf(t, x);
}
__device__ __forceinline__ float4v mfma16(half8 a, half8 b, float4v c) {
    return __builtin_amdgcn_mfma_f32_16x16x32_f16(a, b, c, 0, 0, 0);
}

// B-fragment store helper: element (k, n) of a B operand lives at
// lane = n + 16*((k&31)>>3 & 3), dword = (k&31)>>1 & 3, half = k&1, slab = k>>5.
// Returns HALF-index into the (unsigned*) frag area (256 dw per slab).
__device__ __forceinline__ int bfrag_off(int k, int n) {
    const int slab = k >> 5, k5 = k & 31;
    const int dl = n + 16 * ((k5 >> 3) & 3);
    const int dw = (k5 >> 1) & 3;
    return ((slab * 256 + dl * 4 + dw) << 1) | (k5 & 1);
}

// 16 rows/block, 32 blocks (1/CU), 512 threads. R15 structure (MFMA batching,
// per-lane i/f/g/o activations, B-frag state in LDS) with the critical path
// shortened: (1) x register-prefetch across iterations — the per-step global
// load no longer feeds the same iteration's ds_write/barrier; (2) i=0 and the
// final L2 peeled -> branchless steady-state body with all 5 ds_read_b128
// issued up front so their latencies overlap. R15 profile: VALUBusy 5.6%,
// step = 1990 cy of mostly latency; this targets the x-load chain (~500 cy).
__global__ __launch_bounds__(512)
__attribute__((amdgpu_waves_per_eu(2, 2)))
void lstm3_kernel(
    const float* __restrict__ x,
    const float* __restrict__ Wih1, const float* __restrict__ Whh1,
    const float* __restrict__ bih1, const float* __restrict__ bhh1,
    const float* __restrict__ Wih2, const float* __restrict__ Whh2,
    const float* __restrict__ bih2, const float* __restrict__ bhh2,
    const float* __restrict__ Wfc1, const float* __restrict__ bfc1,
    const float* __restrict__ Wfc2, const float* __restrict__ bfc2,
    const float* __restrict__ Wfc,  const float* __restrict__ bfc,
    float* __restrict__ out)
{
    const int row0 = blockIdx.x * NR;
    const int l    = threadIdx.x;
    const int lane = l & 63;
    const int w    = l >> 6;        // wave 0..7
    const int n    = lane & 15;     // batch col within block
    const int quad = lane >> 4;

    // B-fragment state areas, [parity][slab*256 + lane*4 + dw] dwords.
    // s2f: K=96 (3 slabs): [h1 k=0..31 | h2 k=32..95]
    // s1f: K=64 (2 slabs): [x k=0..13 | pad | h1 k=16..47 | pad k=48..63]
    __shared__ __align__(16) unsigned s2f[2][3 * 256];
    __shared__ __align__(16) unsigned s1f[2][2 * 256];
    __shared__ _Float16 h2plain[NR][H2];
    __shared__ float mlp1[NR][8];
    __shared__ float mlp2[NR][8];

    // ---------------- A-fragments (weights), loaded once ----------------
    half8 a2[2][3];
    float4v bias2[2];
    #pragma unroll
    for (int tt = 0; tt < 2; ++tt) {
        const int T = 2 * w + tt;
        const int m = T * 16 + n;
        const int row = (m & 3) * 64 + (m >> 2);   // orig gate row (i|f|g|o)
        #pragma unroll
        for (int s = 0; s < 3; ++s) {
            const int k0 = s * 32 + quad * 8;
            half8 a;
            if (k0 < H1) {
                #pragma unroll
                for (int j = 0; j < 8; ++j) a[j] = (_Float16)Wih2[row * H1 + k0 + j];
            } else {
                #pragma unroll
                for (int j = 0; j < 8; ++j) a[j] = (_Float16)Whh2[row * H2 + (k0 - H1) + j];
            }
            a2[tt][s] = a;
        }
        const int u = T * 4 + quad;
        #pragma unroll
        for (int r = 0; r < 4; ++r) {
            const int br = r * 64 + u;
            bias2[tt][r] = bih2[br] + bhh2[br];
        }
    }

    half8 a1[2];
    float4v bias1;
    {
        const int m = w * 16 + n;
        const int row = (m & 3) * 32 + (m >> 2);   // 0..127
        #pragma unroll
        for (int s = 0; s < 2; ++s) {
            const int k0 = s * 32 + quad * 8;
            half8 a;
            #pragma unroll
            for (int j = 0; j < 8; ++j) {
                const int k = k0 + j;
                float v = 0.0f;
                if (k < FF)                 v = Wih1[row * FF + k];
                else if (k >= 16 && k < 48) v = Whh1[row * H1 + (k - 16)];
                a[j] = (_Float16)v;
            }
            a1[s] = a;
        }
        const int u1 = w * 4 + quad;
        #pragma unroll
        for (int r = 0; r < 4; ++r) {
            const int br = r * 32 + u1;
            bias1[r] = bih1[br] + bhh1[br];
        }
    }

    // ---------------- precomputed write offsets (half-indices) ----------------
    const int u1   = w * 4 + quad;
    const int offB = bfrag_off(u1, n);              // h1 -> s2f slab0
    const int offA = bfrag_off(16 + u1, n);         // h1 -> s1f
    int off2[2];
    #pragma unroll
    for (int tt = 0; tt < 2; ++tt)
        off2[tt] = bfrag_off(32 + (2 * w + tt) * 4 + quad, n);   // h2 -> s2f

    // x stager (lanes 0..55): 4 elements each over [16 rows][14 feats]
    int offx[4]; const int xact = (l < 56);
    #pragma unroll
    for (int e = 0; e < 4; ++e) {
        const int fi = l * 4 + e;
        const int nr = fi / FF, fe = fi - nr * FF;
        offx[e] = (fi < NR * FF) ? bfrag_off(fe, nr) : -1;
    }
    const size_t xbase = (size_t)row0 * FF + l * 4;

    float c1r = 0.0f;       // layer-1 cell state for (u1, n) — per-lane
    float4 xreg = make_float4(0.f, 0.f, 0.f, 0.f);   // holds x(i+1) at iter i

    // ---------------- init: zero frags, stage x(0), prefetch x(1) ----------------
    for (int z = l; z < 2 * 3 * 256; z += 512) ((unsigned*)s2f)[z] = 0u;
    for (int z = l; z < 2 * 2 * 256; z += 512) ((unsigned*)s1f)[z] = 0u;
    if (xact) {
        const float4 xv = *(const float4*)(x + xbase);            // t = 0
        const float xe[4] = {xv.x, xv.y, xv.z, xv.w};
        #pragma unroll
        for (int e = 0; e < 4; ++e)
            if (offx[e] >= 0) ((_Float16*)s1f[0])[offx[e]] = (_Float16)xe[e];
        xreg = *(const float4*)(x + (size_t)1 * BB * FF + xbase); // t = 1
    }
    __syncthreads();

    // ---------------- i = 0 (peeled): layer-1 only ----------------
    {
        const half8 b0 = *(const half8*)(s1f[0] + lane * 4);
        const half8 b1 = *(const half8*)(s1f[0] + 256 + lane * 4);
        float4v acc = bias1;
        acc = mfma16(a1[0], b0, acc);
        acc = mfma16(a1[1], b1, acc);
        const float cn = sigmoidf_(acc[1]) * c1r + sigmoidf_(acc[0]) * tanhf_(acc[2]);
        c1r = cn;
        const _Float16 hh = (_Float16)(sigmoidf_(acc[3]) * tanhf_(cn));
        ((_Float16*)s1f[1])[offA] = hh;
        ((_Float16*)s2f[0])[offB] = hh;
        if (xact) {
            const float xe[4] = {xreg.x, xreg.y, xreg.z, xreg.w};  // x(1)
            #pragma unroll
            for (int e = 0; e < 4; ++e)
                if (offx[e] >= 0) ((_Float16*)s1f[1])[offx[e]] = (_Float16)xe[e];
            xreg = *(const float4*)(x + (size_t)2 * BB * FF + xbase);  // x(2)
        }
        __syncthreads();
    }

    // ---------------- steady loop: i = 1 .. 511, branchless body ----------------
    for (int i = 1; i < TT; ++i) {
        const int rp = (i - 1) & 1;
        const int cp = i & 1;
        const int np = cp ^ 1;

        // issue ALL state reads first (latencies overlap)
        const half8 sb0 = *(const half8*)(s1f[cp] + lane * 4);
        const half8 sb1 = *(const half8*)(s1f[cp] + 256 + lane * 4);
        const half8 tb0 = *(const half8*)(s2f[rp] + lane * 4);
        const half8 tb1 = *(const half8*)(s2f[rp] + 256 + lane * 4);
        const half8 tb2 = *(const half8*)(s2f[rp] + 512 + lane * 4);

        // ===== layer-1 for step i =====
        {
            float4v acc = bias1;
            acc = mfma16(a1[0], sb0, acc);
            acc = mfma16(a1[1], sb1, acc);
            const float cn = sigmoidf_(acc[1]) * c1r + sigmoidf_(acc[0]) * tanhf_(acc[2]);
            c1r = cn;
            const _Float16 hh = (_Float16)(sigmoidf_(acc[3]) * tanhf_(cn));
            ((_Float16*)s1f[np])[offA] = hh;
            ((_Float16*)s2f[cp])[offB] = hh;
        }
        // ----- stage x(i+1) from xreg (loaded last iteration), reload -----
        if (xact) {
            const float xe[4] = {xreg.x, xreg.y, xreg.z, xreg.w};
            #pragma unroll
            for (int e = 0; e < 4; ++e)
                if (offx[e] >= 0) ((_Float16*)s1f[np])[offx[e]] = (_Float16)xe[e];
            const int tn = (i + 2 < TT) ? (i + 2) : (TT - 1);
            xreg = *(const float4*)(x + (size_t)tn * BB * FF + xbase);
        }

        // ===== layer-2 for step i-1 =====
        #pragma unroll
        for (int tt = 0; tt < 2; ++tt) {
            float4v acc = bias2[tt];
            acc = mfma16(a2[tt][0], tb0, acc);
            acc = mfma16(a2[tt][1], tb1, acc);
            acc = mfma16(a2[tt][2], tb2, acc);
            const float cn = sigmoidf_(acc[0]) * tanhf_(acc[2]);
            const float h  = sigmoidf_(acc[3]) * tanhf_(cn);
            ((_Float16*)s2f[cp])[off2[tt]] = (_Float16)h;
        }
        __syncthreads();
    }

    // ---------------- final layer-2 (step 511) -> h2plain ----------------
    {
        const half8 tb0 = *(const half8*)(s2f[1] + lane * 4);
        const half8 tb1 = *(const half8*)(s2f[1] + 256 + lane * 4);
        const half8 tb2 = *(const half8*)(s2f[1] + 512 + lane * 4);
        #pragma unroll
        for (int tt = 0; tt < 2; ++tt) {
            float4v acc = bias2[tt];
            acc = mfma16(a2[tt][0], tb0, acc);
            acc = mfma16(a2[tt][1], tb1, acc);
            acc = mfma16(a2[tt][2], tb2, acc);
            const float cn = sigmoidf_(acc[0]) * tanhf_(acc[2]);
            const float h  = sigmoidf_(acc[3]) * tanhf_(cn);
            h2plain[n][(2 * w + tt) * 4 + quad] = (_Float16)h;
        }
        __syncthreads();
    }

    // ---------------- MLP head (16 rows) ----------------
    if (l < NR * 8) {
        const int rr = l >> 3, j = l & 7;
        float a = bfc1[j];
        #pragma unroll
        for (int k = 0; k < H2; ++k)
            a = fmaf(fmaxf((float)h2plain[rr][k], 0.0f), Wfc1[j * H2 + k], a);
        mlp1[rr][j] = fmaxf(a, 0.0f);
    }
    __syncthreads();
    if (l < NR * 8) {
        const int rr = l >> 3, j = l & 7;
        float a = bfc2[j];
        #pragma unroll
        for (int k = 0; k < 8; ++k) a = fmaf(mlp1[rr][k], Wfc2[j * 8 + k], a);
        mlp2[rr][j] = fmaxf(a, 0.0f);
    }
    __syncthreads();
    if (l < NR) {
        float a = bfc[0];
        #pragma unroll
        for (int k = 0; k < 8; ++k) a = fmaf(mlp2[l][k], Wfc[k], a);
        out[row0 + l] = a;
    }
}

extern "C" void kernel_launch(void* const* d_in, const int* in_sizes, int n_in,
                              void* d_out, int out_size, void* d_ws, size_t ws_size,
                              hipStream_t stream) {
    const float* x    = (const float*)d_in[0];
    const float* Wih1 = (const float*)d_in[1];
    const float* Whh1 = (const float*)d_in[2];
    const float* bih1 = (const float*)d_in[3];
    const float* bhh1 = (const float*)d_in[4];
    const float* Wih2 = (const float*)d_in[5];
    const float* Whh2 = (const float*)d_in[6];
    const float* bih2 = (const float*)d_in[7];
    const float* bhh2 = (const float*)d_in[8];
    const float* Wfc1 = (const float*)d_in[9];
    const float* bfc1 = (const float*)d_in[10];
    const float* Wfc2 = (const float*)d_in[11];
    const float* bfc2 = (const float*)d_in[12];
    const float* Wfc  = (const float*)d_in[13];
    const float* bfc  = (const float*)d_in[14];
    float* out = (float*)d_out;

    lstm3_kernel<<<dim3(NBLK), dim3(512), 0, stream>>>(
        x, Wih1, Whh1, bih1, bhh1, Wih2, Whh2, bih2, bhh2,
        Wfc1, bfc1, Wfc2, bfc2, Wfc, bfc, out);
}